// Round 16
// baseline (270.500 us; speedup 1.0000x reference)
//
#include <hip/hip_runtime.h>

#define NQ   64
#define CCH  1024
#define DSP  1024      // 32*32 spatial
#define NSUP 25600     // 25*32*32
#define NKT  400       // total K-tiles of 64 over NSUP
#define NCOVB 252      // 36 upper 128-pairs x 7 K-slices

typedef __attribute__((ext_vector_type(4))) float f32x4;
typedef __attribute__((ext_vector_type(8))) __bf16 bf16x8;

#define WAITVM(N) asm volatile("s_waitcnt vmcnt(" #N ")" ::: "memory")
#define WAITLGKM0() asm volatile("s_waitcnt lgkmcnt(0)" ::: "memory")
#define BAR() __builtin_amdgcn_s_barrier()
#define SCHED0() __builtin_amdgcn_sched_barrier(0)

__device__ inline unsigned short f2bf(float x) {
  unsigned u = __builtin_bit_cast(unsigned, x);
  u += 0x7fffu + ((u >> 16) & 1u);
  return (unsigned short)(u >> 16);
}

// ---------------- prep: mean+center+cast, fused with cov/out zeroing ----------------
// one block per channel c: single HBM pass, row cached in REGISTERS
// (640 thr x 10 float4, statically indexed) — ~3 blocks/CU of TLP.
__global__ __launch_bounds__(640) void mean_center_kernel(
    const float* __restrict__ sup, float* __restrict__ mean,
    unsigned short* __restrict__ Sb, int write_sb,
    float4* __restrict__ cov4, float4* __restrict__ out4) {
  __shared__ float wred[10];
  __shared__ float mbc;
  const int c = blockIdx.x;
  const int tid = threadIdx.x;
  const int l = tid & 63, wid = tid >> 6;
  const float4 z4 = make_float4(0.f, 0.f, 0.f, 0.f);
  if (tid < 256) cov4[c * 256 + tid] = z4;           // 1024 blocks x 4 KB = 4 MB
  if (c == 0 && tid >= 256 && tid < 272) out4[tid - 256] = z4;

  float4 v[10];
  float s = 0.f;
#pragma unroll
  for (int i = 0; i < 10; ++i) {
    const int qd = i * 640 + tid;
    const int b = qd >> 8, s4 = (qd & 255) << 2;
    v[i] = *(const float4*)(sup + ((size_t)b * CCH + c) * DSP + s4);
    s += v[i].x + v[i].y + v[i].z + v[i].w;
  }
#pragma unroll
  for (int off = 32; off > 0; off >>= 1) s += __shfl_xor(s, off);
  if (l == 0) wred[wid] = s;
  __syncthreads();
  if (tid == 0) {
    float t = 0.f;
#pragma unroll
    for (int i = 0; i < 10; ++i) t += wred[i];
    mbc = t * (1.0f / 25600.0f);
  }
  __syncthreads();
  const float m = mbc;
  if (tid == 0) mean[c] = m;
  if (write_sb) {
#pragma unroll
    for (int i = 0; i < 10; ++i) {
      const int qd = i * 640 + tid;
      const int b = qd >> 8, s4 = (qd & 255) << 2;
      ushort4 o;
      o.x = f2bf(v[i].x - m); o.y = f2bf(v[i].y - m);
      o.z = f2bf(v[i].z - m); o.w = f2bf(v[i].w - m);
      *(ushort4*)(Sb + (size_t)c * NSUP + b * DSP + s4) = o;
    }
  }
}

// standalone qnorm (thin-ws fallback path only)
__global__ __launch_bounds__(256) void qnorm_kernel(
    const float* __restrict__ q, float* __restrict__ qfac,
    unsigned short* __restrict__ Qb, int write_qb) {
  const int row = blockIdx.x * 4 + (threadIdx.x >> 6);
  const int l = threadIdx.x & 63;
  const float4* src = (const float4*)(q + (size_t)row * DSP);
  float4 v[4];
  float ss = 0.f;
#pragma unroll
  for (int i = 0; i < 4; ++i) {
    v[i] = src[l + 64 * i];
    ss += v[i].x * v[i].x + v[i].y * v[i].y + v[i].z * v[i].z + v[i].w * v[i].w;
  }
#pragma unroll
  for (int off = 32; off > 0; off >>= 1) ss += __shfl_xor(ss, off);
  const float f = 1.0f / (sqrtf(ss) + 1e-8f);
  if (l == 0) qfac[row] = f;
  if (write_qb) {
#pragma unroll
    for (int i = 0; i < 4; ++i) {
      ushort4 o;
      o.x = f2bf(v[i].x * f); o.y = f2bf(v[i].y * f);
      o.z = f2bf(v[i].z * f); o.w = f2bf(v[i].w * f);
      *(ushort4*)(Qb + (size_t)row * DSP + (size_t)(l + 64 * i) * 4) = o;
    }
  }
}

// ---------------- shared fragment helpers ----------------
// LDS tiles XOR-swizzled: logical (r,c) at r*64 + (c ^ ((r&7)<<3)).
// global_load_lds writes linearly -> SOURCE column pre-swizzled (rule #21).

__device__ inline void rd4(const unsigned short* base, int r0, int col, int lr, bf16x8 f[4]) {
#pragma unroll
  for (int i = 0; i < 4; ++i)
    f[i] = *(const bf16x8*)(const void*)(base + (r0 + i * 16 + lr) * 64 + col);
}
// no setprio (m190: negative on barrier-lockstep 2-phase GEMM loops)
__device__ inline void mfma16(const bf16x8 a[4], const bf16x8 b[4], f32x4 (*acc)[4]) {
#pragma unroll
  for (int i = 0; i < 4; ++i)
#pragma unroll
    for (int j = 0; j < 4; ++j)
      acc[i][j] = __builtin_amdgcn_mfma_f32_16x16x32_bf16(a[i], b[j], acc[i][j], 0, 0, 0);
}

// stage a 128x64 bf16 tile (256-thread blocks): exactly 4 global_load_lds/thread
__device__ inline void stage_glds(const unsigned short* __restrict__ src, int ld,
                                  int row0, int k0, unsigned short* lds) {
  const int tid = threadIdx.x;
  const int w = tid >> 6;
#pragma unroll
  for (int it = 0; it < 4; ++it) {
    const int ci = it * 256 + tid;
    const int r = ci >> 3;
    const int kc = ((ci & 7) ^ (r & 7)) << 3;
    const unsigned short* g = src + (size_t)(row0 + r) * ld + k0 + kc;
    unsigned short* lb = lds + ((it * 256 + w * 64) << 3);
    __builtin_amdgcn_global_load_lds((const __attribute__((address_space(1))) void*)g,
                                     (__attribute__((address_space(3))) void*)lb,
                                     16, 0, 0);
  }
}

__device__ inline void decode_tile8(int t, int& ti, int& tj) {
  int rem = t; ti = 0;
  while (rem >= 8 - ti) { rem -= 8 - ti; ++ti; }
  tj = ti + rem;
}

// ---------------- fused cov + qnorm kernel ----------------
// blocks 0..251: cov 128-pair x K-slice jobs (MFMA-bound, 64 KB LDS, dbuf).
// blocks 252..16635: qnorm jobs (HBM-bound) — co-resident, phases overlap.
__global__ __launch_bounds__(256) void covq_kernel(
    const unsigned short* __restrict__ Sb, float* __restrict__ cov,
    const float* __restrict__ q, float* __restrict__ qfac,
    unsigned short* __restrict__ Qb) {
  __shared__ unsigned short clds[32768];   // 2 bufs x (A 8192 | B 8192) elems
  const int bx = blockIdx.x;
  if (bx < NCOVB) {
    // ---- cov job: slice s covers K-tiles [400s/7, 400(s+1)/7) ----
    const int ks = bx % 7;
    int ti, tj; decode_tile8(bx / 7, ti, tj);
    const bool diag = (ti == tj);
    const int tid = threadIdx.x, l = tid & 63, w = tid >> 6;
    const int wr = (w >> 1) * 64, wc = (w & 1) * 64, lr = l & 15, kg = (l >> 4) * 8;
    const int sw = (lr & 7) << 3;
    f32x4 acc[4][4];
#pragma unroll
    for (int i = 0; i < 4; ++i)
#pragma unroll
      for (int j = 0; j < 4; ++j) acc[i][j] = 0.f;

    const int kt0 = (NKT * ks) / 7;
    const int nt = (NKT * (ks + 1)) / 7 - kt0;
    const int kbase = kt0 * 64;

    stage_glds(Sb, NSUP, ti * 128, kbase, clds);
    if (!diag) stage_glds(Sb, NSUP, tj * 128, kbase, clds + 8192);
    stage_glds(Sb, NSUP, ti * 128, kbase + 64, clds + 16384);
    if (!diag) stage_glds(Sb, NSUP, tj * 128, kbase + 64, clds + 16384 + 8192);
    for (int t = 0; t < nt; ++t) {
      const int cb = (t & 1) * 16384;
      if (t < nt - 1) { if (diag) { WAITVM(4); } else { WAITVM(8); } }
      else { WAITVM(0); }
      BAR(); SCHED0();
      const unsigned short* A = clds + cb;
      const unsigned short* B = diag ? A : A + 8192;
      const int col0 = kg ^ sw, col1 = (32 + kg) ^ sw;
      bf16x8 a[4], b[4];
      rd4(A, wr, col0, lr, a);
      rd4(B, wc, col0, lr, b);
      mfma16(a, b, (f32x4(*)[4])acc);
      rd4(A, wr, col1, lr, a);
      rd4(B, wc, col1, lr, b);
      WAITLGKM0();
      BAR(); SCHED0();
      if (t + 2 < nt) {
        const int k2 = kbase + (t + 2) * 64;
        stage_glds(Sb, NSUP, ti * 128, k2, clds + cb);
        if (!diag) stage_glds(Sb, NSUP, tj * 128, k2, clds + cb + 8192);
      }
      mfma16(a, b, (f32x4(*)[4])acc);
    }

    const float scale = 1.0f / (25599.0f + 1e-8f);
    const int rbase = ti * 128 + wr + (l >> 4) * 4;
    const int cbase = tj * 128 + wc + (l & 15);
#pragma unroll
    for (int i = 0; i < 4; ++i)
#pragma unroll
      for (int j = 0; j < 4; ++j)
#pragma unroll
        for (int r = 0; r < 4; ++r)
          atomicAdd(&cov[(size_t)(rbase + i * 16 + r) * CCH + cbase + j * 16],
                    acc[i][j][r] * scale);
  } else {
    // ---- qnorm job: 4 rows per block ----
    const int row = (bx - NCOVB) * 4 + (threadIdx.x >> 6);
    const int l = threadIdx.x & 63;
    const float4* src = (const float4*)(q + (size_t)row * DSP);
    float4 v[4];
    float ss = 0.f;
#pragma unroll
    for (int i = 0; i < 4; ++i) {
      v[i] = src[l + 64 * i];
      ss += v[i].x * v[i].x + v[i].y * v[i].y + v[i].z * v[i].z + v[i].w * v[i].w;
    }
#pragma unroll
    for (int off = 32; off > 0; off >>= 1) ss += __shfl_xor(ss, off);
    const float f = 1.0f / (sqrtf(ss) + 1e-8f);
    if (l == 0) qfac[row] = f;
#pragma unroll
    for (int i = 0; i < 4; ++i) {
      ushort4 o;
      o.x = f2bf(v[i].x * f); o.y = f2bf(v[i].y * f);
      o.z = f2bf(v[i].z * f); o.w = f2bf(v[i].w * f);
      *(ushort4*)(Qb + (size_t)row * DSP + (size_t)(l + 64 * i) * 4) = o;
    }
  }
}

// ---------------- gram128: per-query Gram x cov Frobenius, m97 structure ----------------
// 2304 blocks = 8 xcd * 8 n * 36 upper-128-pairs; 256 thr, 32 KB LDS single-
// buffered -> ~5 blocks/CU: cross-block wave overlap (m114) hides the per-step
// stage drain (m97's 874 TF structure; dbuf adds nothing there per m99/m100).
// 128-pairs align 1:1 with cov's upper-128-blocks -> exact, plain x2 off-diag.
__global__ __launch_bounds__(256) void gram128_kernel(
    const unsigned short* __restrict__ Qb, const float* __restrict__ cov,
    float* __restrict__ out) {
  __shared__ unsigned short lA[8192];
  __shared__ unsigned short lB[8192];
  const int wg = blockIdx.x;
  const int xcd = wg & 7, slot = wg >> 3;        // slot 0..287
  const int n = xcd * 8 + slot / 36;
  int ti, tj; decode_tile8(slot % 36, ti, tj);
  const bool diag = (ti == tj);
  const int tid = threadIdx.x, l = tid & 63, w = tid >> 6;
  const int wr = (w >> 1) * 64, wc = (w & 1) * 64, lr = l & 15, kg = (l >> 4) * 8;
  const int sw = (lr & 7) << 3;
  const unsigned short* Qn = Qb + (size_t)n * CCH * DSP;

  f32x4 acc[4][4];
#pragma unroll
  for (int i = 0; i < 4; ++i)
#pragma unroll
    for (int j = 0; j < 4; ++j) acc[i][j] = 0.f;

  for (int kt = 0; kt < 16; ++kt) {
    stage_glds(Qn, DSP, ti * 128, kt * 64, lA);
    if (!diag) stage_glds(Qn, DSP, tj * 128, kt * 64, lB);
    __syncthreads();                     // drains vmcnt: tile ready
    const unsigned short* B = diag ? lA : lB;
    const int col0 = kg ^ sw, col1 = (32 + kg) ^ sw;
    bf16x8 a[4], b[4];
    rd4(lA, wr, col0, lr, a);
    rd4(B, wc, col0, lr, b);
    mfma16(a, b, (f32x4(*)[4])acc);
    rd4(lA, wr, col1, lr, a);
    rd4(B, wc, col1, lr, b);
    mfma16(a, b, (f32x4(*)[4])acc);
    __syncthreads();                     // all waves done before overwrite
  }

  float s = 0.f;
  const int rbase = ti * 128 + wr + (l >> 4) * 4;
  const int cbase = tj * 128 + wc + (l & 15);
#pragma unroll
  for (int i = 0; i < 4; ++i)
#pragma unroll
    for (int j = 0; j < 4; ++j)
#pragma unroll
      for (int r = 0; r < 4; ++r)
        s += acc[i][j][r] * cov[(size_t)(rbase + i * 16 + r) * CCH + cbase + j * 16];
  if (!diag) s *= 2.0f;
  s *= (1.0f / 1024.0f);
#pragma unroll
  for (int off = 32; off > 0; off >>= 1) s += __shfl_xor(s, off);
  if (l == 0) atomicAdd(&out[n], s);
}

// ---------------- f32 reg-staged fallback path (thin ws) — 128-tile scheme ----------------
__device__ inline void mfma16s(const bf16x8 a[4], const bf16x8 b[4], f32x4 acc[4][4]) {
#pragma unroll
  for (int i = 0; i < 4; ++i)
#pragma unroll
    for (int j = 0; j < 4; ++j)
      acc[i][j] = __builtin_amdgcn_mfma_f32_16x16x32_bf16(a[i], b[j], acc[i][j], 0, 0, 0);
}

__device__ inline void stage_sup_f32(const float* __restrict__ sup,
                                     const float* __restrict__ mean,
                                     int row0, int k0, unsigned short* lds) {
  const int tid = threadIdx.x;
#pragma unroll
  for (int it = 0; it < 4; ++it) {
    const int ci = it * 256 + tid;
    const int r = ci >> 3, kc = (ci & 7) << 3;
    const int c = row0 + r;
    const int k = k0 + kc;
    const int b = k >> 10, sp = k & 1023;
    const float4* gp = (const float4*)(sup + ((size_t)b * CCH + c) * DSP + sp);
    const float4 v0 = gp[0], v1 = gp[1];
    const float m = mean[c];
    union { unsigned short h[8]; int4 q; } pk;
    pk.h[0] = f2bf(v0.x - m); pk.h[1] = f2bf(v0.y - m);
    pk.h[2] = f2bf(v0.z - m); pk.h[3] = f2bf(v0.w - m);
    pk.h[4] = f2bf(v1.x - m); pk.h[5] = f2bf(v1.y - m);
    pk.h[6] = f2bf(v1.z - m); pk.h[7] = f2bf(v1.w - m);
    *(int4*)(lds + (size_t)(r * 8 + ((ci & 7) ^ (r & 7))) * 8) = pk.q;
  }
}
__device__ inline void stage_q_f32(const float* __restrict__ qn,
                                   const float* __restrict__ qfacn,
                                   int row0, int k0, unsigned short* lds) {
  const int tid = threadIdx.x;
#pragma unroll
  for (int it = 0; it < 4; ++it) {
    const int ci = it * 256 + tid;
    const int r = ci >> 3, kc = (ci & 7) << 3;
    const int c = row0 + r;
    const float4* gp = (const float4*)(qn + (size_t)c * DSP + k0 + kc);
    const float4 v0 = gp[0], v1 = gp[1];
    const float f = qfacn[c];
    union { unsigned short h[8]; int4 q; } pk;
    pk.h[0] = f2bf(v0.x * f); pk.h[1] = f2bf(v0.y * f);
    pk.h[2] = f2bf(v0.z * f); pk.h[3] = f2bf(v0.w * f);
    pk.h[4] = f2bf(v1.x * f); pk.h[5] = f2bf(v1.y * f);
    pk.h[6] = f2bf(v1.z * f); pk.h[7] = f2bf(v1.w * f);
    *(int4*)(lds + (size_t)(r * 8 + ((ci & 7) ^ (r & 7))) * 8) = pk.q;
  }
}
__device__ inline void compute_step(const unsigned short* lA, const unsigned short* lB,
                                    int wr, int wc, int lr, int kg, f32x4 acc[4][4]) {
  const int sc = (lr & 7) << 3;
#pragma unroll
  for (int kk = 0; kk < 64; kk += 32) {
    const int col = (kk + kg) ^ sc;
    bf16x8 a[4], b[4];
    rd4(lA, wr, col, lr, a);
    rd4(lB, wc, col, lr, b);
    mfma16s(a, b, acc);
  }
}

__global__ __launch_bounds__(256) void cov_kernel_f32(
    const float* __restrict__ sup, const float* __restrict__ mean,
    float* __restrict__ cov) {
  __shared__ unsigned short clds[32768];
  const int wg = blockIdx.x;
  const int ks = wg & 7;
  int ti, tj; decode_tile8(wg >> 3, ti, tj);
  const bool diag = (ti == tj);
  const int tid = threadIdx.x, l = tid & 63, w = tid >> 6;
  const int wr = (w >> 1) * 64, wc = (w & 1) * 64, lr = l & 15, kg = (l >> 4) * 8;
  f32x4 acc[4][4];
#pragma unroll
  for (int i = 0; i < 4; ++i)
#pragma unroll
    for (int j = 0; j < 4; ++j) acc[i][j] = 0.f;

  const int kbase = ks * (NSUP / 8);
  stage_sup_f32(sup, mean, ti * 128, kbase, clds);
  if (!diag) stage_sup_f32(sup, mean, tj * 128, kbase, clds + 8192);
  __syncthreads();
  for (int kt = 0; kt < 50; ++kt) {
    const int cb = (kt & 1) * 16384;
    const int nb = cb ^ 16384;
    if (kt + 1 < 50) {
      const int k1 = kbase + (kt + 1) * 64;
      stage_sup_f32(sup, mean, ti * 128, k1, clds + nb);
      if (!diag) stage_sup_f32(sup, mean, tj * 128, k1, clds + nb + 8192);
    }
    compute_step(clds + cb, diag ? clds + cb : clds + cb + 8192, wr, wc, lr, kg, acc);
    __syncthreads();
  }
  const float scale = 1.0f / (25599.0f + 1e-8f);
  const int rbase = ti * 128 + wr + (l >> 4) * 4;
  const int cbase = tj * 128 + wc + (l & 15);
#pragma unroll
  for (int i = 0; i < 4; ++i)
#pragma unroll
    for (int j = 0; j < 4; ++j)
#pragma unroll
      for (int r = 0; r < 4; ++r)
        atomicAdd(&cov[(size_t)(rbase + i * 16 + r) * CCH + cbase + j * 16],
                  acc[i][j][r] * scale);
}

__global__ __launch_bounds__(256) void gram_kernel_f32(
    const float* __restrict__ q, const float* __restrict__ qfac,
    const float* __restrict__ cov, float* __restrict__ out) {
  __shared__ unsigned short lA[2][128 * 64];
  __shared__ unsigned short lB[2][128 * 64];
  const int wg = blockIdx.x;
  const int xcd = wg & 7, slot = wg >> 3;
  const int n = xcd * 8 + slot / 36;
  int ti, tj; decode_tile8(slot % 36, ti, tj);
  const bool diag = (ti == tj);
  const int tid = threadIdx.x, l = tid & 63, w = tid >> 6;
  const int wr = (w >> 1) * 64, wc = (w & 1) * 64, lr = l & 15, kg = (l >> 4) * 8;
  f32x4 acc[4][4];
#pragma unroll
  for (int i = 0; i < 4; ++i)
#pragma unroll
    for (int j = 0; j < 4; ++j) acc[i][j] = 0.f;

  const float* qn = q + (size_t)n * CCH * DSP;
  const float* qfacn = qfac + (size_t)n * CCH;

  stage_q_f32(qn, qfacn, ti * 128, 0, lA[0]);
  if (!diag) stage_q_f32(qn, qfacn, tj * 128, 0, lB[0]);
  __syncthreads();
  int cur = 0;
  for (int kt = 0; kt < 16; ++kt) {
    if (kt + 1 < 16) {
      const int k1 = (kt + 1) * 64;
      stage_q_f32(qn, qfacn, ti * 128, k1, lA[cur ^ 1]);
      if (!diag) stage_q_f32(qn, qfacn, tj * 128, k1, lB[cur ^ 1]);
    }
    compute_step(lA[cur], diag ? lA[cur] : lB[cur], wr, wc, lr, kg, acc);
    __syncthreads();
    cur ^= 1;
  }

  float s = 0.f;
  const int rbase = ti * 128 + wr + (l >> 4) * 4;
  const int cbase = tj * 128 + wc + (l & 15);
#pragma unroll
  for (int i = 0; i < 4; ++i)
#pragma unroll
    for (int j = 0; j < 4; ++j)
#pragma unroll
      for (int r = 0; r < 4; ++r)
        s += acc[i][j][r] * cov[(size_t)(rbase + i * 16 + r) * CCH + cbase + j * 16];
  if (!diag) s *= 2.0f;
  s *= (1.0f / 1024.0f);
#pragma unroll
  for (int off = 32; off > 0; off >>= 1) s += __shfl_xor(s, off);
  if (l == 0) atomicAdd(&out[n], s);
}

// ---------------- launch ----------------
extern "C" void kernel_launch(void* const* d_in, const int* in_sizes, int n_in,
                              void* d_out, int out_size, void* d_ws, size_t ws_size,
                              hipStream_t stream) {
  const float* q = (const float*)d_in[0];
  const float* sup = (const float*)d_in[1];
  float* out = (float*)d_out;

  char* ws = (char*)d_ws;
  float* mean = (float*)ws;                                  // 4 KB
  float* qfac = (float*)(ws + (4 << 10));                    // 256 KB
  float* cov  = (float*)(ws + (4 << 10) + (256 << 10));      // 4 MB
  unsigned short* Sb = (unsigned short*)(ws + (4 << 10) + (256 << 10) + (4 << 20));
  unsigned short* Qb = Sb + (size_t)CCH * NSUP;
  const size_t need_fat = (size_t)(4 << 10) + (256 << 10) + (4 << 20) +
                          (size_t)CCH * NSUP * 2 + (size_t)NQ * CCH * DSP * 2;
  const bool fat = ws_size >= need_fat;

  mean_center_kernel<<<CCH, 640, 0, stream>>>(sup, mean, Sb, fat ? 1 : 0,
                                              (float4*)cov, (float4*)out);

  if (fat) {
    covq_kernel<<<dim3(NCOVB + NQ * CCH / 4), 256, 0, stream>>>(Sb, cov, q, qfac, Qb);
    gram128_kernel<<<dim3(2304), 256, 0, stream>>>(Qb, cov, out);
  } else {
    qnorm_kernel<<<NQ * CCH / 4, 256, 0, stream>>>(q, qfac, (unsigned short*)0, 0);
    cov_kernel_f32<<<dim3(288), 256, 0, stream>>>(sup, mean, cov);
    gram_kernel_f32<<<dim3(8 * 8 * 36), 256, 0, stream>>>(q, qfac, cov, out);
  }
}

// Round 17
// 253.884 us; speedup vs baseline: 1.0654x; 1.0654x over previous
//
#include <hip/hip_runtime.h>

#define NQ   64
#define CCH  1024
#define DSP  1024      // 32*32 spatial
#define NSUP 25600     // 25*32*32
#define NKT  400       // total K-tiles of 64 over NSUP
#define NCOVB 252      // 36 upper 128-pairs x 7 K-slices

typedef __attribute__((ext_vector_type(4))) float f32x4;
typedef __attribute__((ext_vector_type(8))) __bf16 bf16x8;

#define WAITVM(N) asm volatile("s_waitcnt vmcnt(" #N ")" ::: "memory")
#define WAITLGKM0() asm volatile("s_waitcnt lgkmcnt(0)" ::: "memory")
#define BAR() __builtin_amdgcn_s_barrier()
#define SCHED0() __builtin_amdgcn_sched_barrier(0)

__device__ inline unsigned short f2bf(float x) {
  unsigned u = __builtin_bit_cast(unsigned, x);
  u += 0x7fffu + ((u >> 16) & 1u);
  return (unsigned short)(u >> 16);
}

// ---------------- prep: mean+center+cast, fused with cov/out zeroing ----------------
// one block per channel c: single HBM pass, row cached in REGISTERS
// (640 thr x 10 float4, statically indexed) — ~3 blocks/CU of TLP.
__global__ __launch_bounds__(640) void mean_center_kernel(
    const float* __restrict__ sup, float* __restrict__ mean,
    unsigned short* __restrict__ Sb, int write_sb,
    float4* __restrict__ cov4, float4* __restrict__ out4) {
  __shared__ float wred[10];
  __shared__ float mbc;
  const int c = blockIdx.x;
  const int tid = threadIdx.x;
  const int l = tid & 63, wid = tid >> 6;
  const float4 z4 = make_float4(0.f, 0.f, 0.f, 0.f);
  if (tid < 256) cov4[c * 256 + tid] = z4;           // 1024 blocks x 4 KB = 4 MB
  if (c == 0 && tid >= 256 && tid < 272) out4[tid - 256] = z4;

  float4 v[10];
  float s = 0.f;
#pragma unroll
  for (int i = 0; i < 10; ++i) {
    const int qd = i * 640 + tid;
    const int b = qd >> 8, s4 = (qd & 255) << 2;
    v[i] = *(const float4*)(sup + ((size_t)b * CCH + c) * DSP + s4);
    s += v[i].x + v[i].y + v[i].z + v[i].w;
  }
#pragma unroll
  for (int off = 32; off > 0; off >>= 1) s += __shfl_xor(s, off);
  if (l == 0) wred[wid] = s;
  __syncthreads();
  if (tid == 0) {
    float t = 0.f;
#pragma unroll
    for (int i = 0; i < 10; ++i) t += wred[i];
    mbc = t * (1.0f / 25600.0f);
  }
  __syncthreads();
  const float m = mbc;
  if (tid == 0) mean[c] = m;
  if (write_sb) {
#pragma unroll
    for (int i = 0; i < 10; ++i) {
      const int qd = i * 640 + tid;
      const int b = qd >> 8, s4 = (qd & 255) << 2;
      ushort4 o;
      o.x = f2bf(v[i].x - m); o.y = f2bf(v[i].y - m);
      o.z = f2bf(v[i].z - m); o.w = f2bf(v[i].w - m);
      *(ushort4*)(Sb + (size_t)c * NSUP + b * DSP + s4) = o;
    }
  }
}

// standalone qnorm (thin-ws fallback path only)
__global__ __launch_bounds__(256) void qnorm_kernel(
    const float* __restrict__ q, float* __restrict__ qfac,
    unsigned short* __restrict__ Qb, int write_qb) {
  const int row = blockIdx.x * 4 + (threadIdx.x >> 6);
  const int l = threadIdx.x & 63;
  const float4* src = (const float4*)(q + (size_t)row * DSP);
  float4 v[4];
  float ss = 0.f;
#pragma unroll
  for (int i = 0; i < 4; ++i) {
    v[i] = src[l + 64 * i];
    ss += v[i].x * v[i].x + v[i].y * v[i].y + v[i].z * v[i].z + v[i].w * v[i].w;
  }
#pragma unroll
  for (int off = 32; off > 0; off >>= 1) ss += __shfl_xor(ss, off);
  const float f = 1.0f / (sqrtf(ss) + 1e-8f);
  if (l == 0) qfac[row] = f;
  if (write_qb) {
#pragma unroll
    for (int i = 0; i < 4; ++i) {
      ushort4 o;
      o.x = f2bf(v[i].x * f); o.y = f2bf(v[i].y * f);
      o.z = f2bf(v[i].z * f); o.w = f2bf(v[i].w * f);
      *(ushort4*)(Qb + (size_t)row * DSP + (size_t)(l + 64 * i) * 4) = o;
    }
  }
}

// ---------------- shared fragment helpers ----------------
// LDS tiles XOR-swizzled: logical (r,c) at r*64 + (c ^ ((r&7)<<3)).
// global_load_lds writes linearly -> SOURCE column pre-swizzled (rule #21).

__device__ inline void rd4(const unsigned short* base, int r0, int col, int lr, bf16x8 f[4]) {
#pragma unroll
  for (int i = 0; i < 4; ++i)
    f[i] = *(const bf16x8*)(const void*)(base + (r0 + i * 16 + lr) * 64 + col);
}
// no setprio (m190: negative on barrier-lockstep 2-phase GEMM loops)
__device__ inline void mfma16(const bf16x8 a[4], const bf16x8 b[4], f32x4 (*acc)[4]) {
#pragma unroll
  for (int i = 0; i < 4; ++i)
#pragma unroll
    for (int j = 0; j < 4; ++j)
      acc[i][j] = __builtin_amdgcn_mfma_f32_16x16x32_bf16(a[i], b[j], acc[i][j], 0, 0, 0);
}

// stage a 128x64 bf16 tile (256-thread blocks): exactly 4 global_load_lds/thread
__device__ inline void stage_glds(const unsigned short* __restrict__ src, int ld,
                                  int row0, int k0, unsigned short* lds) {
  const int tid = threadIdx.x;
  const int w = tid >> 6;
#pragma unroll
  for (int it = 0; it < 4; ++it) {
    const int ci = it * 256 + tid;
    const int r = ci >> 3;
    const int kc = ((ci & 7) ^ (r & 7)) << 3;
    const unsigned short* g = src + (size_t)(row0 + r) * ld + k0 + kc;
    unsigned short* lb = lds + ((it * 256 + w * 64) << 3);
    __builtin_amdgcn_global_load_lds((const __attribute__((address_space(1))) void*)g,
                                     (__attribute__((address_space(3))) void*)lb,
                                     16, 0, 0);
  }
}

// stage a 256x64 bf16 tile (512-thread blocks): exactly 4 global_load_lds/thread
// layout: (r>>7)*8192 + (r&127)*64 + swizzled col
__device__ inline void stage256g(const unsigned short* __restrict__ src, int ld,
                                 int row0, int k0, unsigned short* lds_base) {
  const int tid = threadIdx.x;
  const int wid = tid >> 6;
#pragma unroll
  for (int it = 0; it < 4; ++it) {
    const int ci = it * 512 + tid;          // chunk 0..2047 (16B each)
    const int r = ci >> 3;
    const int kc = ((ci & 7) ^ (r & 7)) << 3;
    const unsigned short* g = src + (size_t)(row0 + r) * ld + k0 + kc;
    unsigned short* lb = lds_base + ((it * 512 + (wid << 6)) << 3);
    __builtin_amdgcn_global_load_lds((const __attribute__((address_space(1))) void*)g,
                                     (__attribute__((address_space(3))) void*)lb,
                                     16, 0, 0);
  }
}

// NT K-tiles of 64 starting at k0; 2-phase schedule: counted vmcnt at tile top,
// one mid-tile lgkm0+BAR free point, stage(t+2) after it.
// LDS 128 KB: buf b at b*32768 elems: A [0,16384), B [16384,32768).
template <int NT>
__device__ inline void loop256(const unsigned short* __restrict__ src, int ld,
                               int rowA, int rowB, int k0, bool diag,
                               unsigned short* lds,
                               int wm, int wn, int lr, int kg, int sw,
                               f32x4 (*acc)[4]) {
  stage256g(src, ld, rowA, k0, lds);
  if (!diag) stage256g(src, ld, rowB, k0, lds + 16384);
  stage256g(src, ld, rowA, k0 + 64, lds + 32768);
  if (!diag) stage256g(src, ld, rowB, k0 + 64, lds + 32768 + 16384);

  for (int t = 0; t < NT; ++t) {
    const int cb = (t & 1) << 15;
    if (t < NT - 1) { if (diag) { WAITVM(4); } else { WAITVM(8); } }
    else { WAITVM(0); }
    BAR(); SCHED0();
    const unsigned short* A = lds + cb + wm * 8192;
    const unsigned short* B = lds + cb + (diag ? 0 : 16384) + (wn >> 1) * 8192;
    const int brow = (wn & 1) * 64;
    bf16x8 a[4], b[4];
    {
      const int col = kg ^ sw;
      rd4(B, brow, col, lr, b);
      rd4(A, 0, col, lr, a);
      mfma16(a, b, &acc[0]);
      rd4(A, 64, col, lr, a);
      mfma16(a, b, &acc[4]);
    }
    {
      const int col = (32 + kg) ^ sw;
      rd4(B, brow, col, lr, b);
      rd4(A, 0, col, lr, a);
      mfma16(a, b, &acc[0]);
      rd4(A, 64, col, lr, a);
      WAITLGKM0();
      BAR(); SCHED0();                   // all waves done reading buf cb
      if (t + 2 < NT) {
        stage256g(src, ld, rowA, k0 + (t + 2) * 64, lds + cb);
        if (!diag) stage256g(src, ld, rowB, k0 + (t + 2) * 64, lds + cb + 16384);
      }
      mfma16(a, b, &acc[4]);
    }
  }
}

__device__ inline void decode_tile8(int t, int& ti, int& tj) {
  int rem = t; ti = 0;
  while (rem >= 8 - ti) { rem -= 8 - ti; ++ti; }
  tj = ti + rem;
}
__device__ inline void decode_pair4(int p, int& ti, int& tj) {
  int rem = p; ti = 0;
  while (rem >= 4 - ti) { rem -= 4 - ti; ++ti; }
  tj = ti + rem;
}

// ---------------- fused cov + qnorm kernel ----------------
// blocks 0..251: cov 128-pair x K-slice jobs (MFMA-bound, 64 KB LDS).
// blocks 252..: qnorm jobs (HBM-bound, no LDS use) — co-resident with cov
// blocks, so the two independent phases overlap.
__global__ __launch_bounds__(256) void covq_kernel(
    const unsigned short* __restrict__ Sb, float* __restrict__ cov,
    const float* __restrict__ q, float* __restrict__ qfac,
    unsigned short* __restrict__ Qb) {
  __shared__ unsigned short clds[32768];   // 2 bufs x (A 8192 | B 8192) elems
  const int bx = blockIdx.x;
  if (bx < NCOVB) {
    // ---- cov job: slice s covers K-tiles [400s/7, 400(s+1)/7) ----
    const int ks = bx % 7;
    int ti, tj; decode_tile8(bx / 7, ti, tj);
    const bool diag = (ti == tj);
    const int tid = threadIdx.x, l = tid & 63, w = tid >> 6;
    const int wr = (w >> 1) * 64, wc = (w & 1) * 64, lr = l & 15, kg = (l >> 4) * 8;
    const int sw = (lr & 7) << 3;
    f32x4 acc[4][4];
#pragma unroll
    for (int i = 0; i < 4; ++i)
#pragma unroll
      for (int j = 0; j < 4; ++j) acc[i][j] = 0.f;

    const int kt0 = (NKT * ks) / 7;
    const int nt = (NKT * (ks + 1)) / 7 - kt0;
    const int kbase = kt0 * 64;

    stage_glds(Sb, NSUP, ti * 128, kbase, clds);
    if (!diag) stage_glds(Sb, NSUP, tj * 128, kbase, clds + 8192);
    stage_glds(Sb, NSUP, ti * 128, kbase + 64, clds + 16384);
    if (!diag) stage_glds(Sb, NSUP, tj * 128, kbase + 64, clds + 16384 + 8192);
    for (int t = 0; t < nt; ++t) {
      const int cb = (t & 1) * 16384;
      if (t < nt - 1) { if (diag) { WAITVM(4); } else { WAITVM(8); } }
      else { WAITVM(0); }
      BAR(); SCHED0();
      const unsigned short* A = clds + cb;
      const unsigned short* B = diag ? A : A + 8192;
      const int col0 = kg ^ sw, col1 = (32 + kg) ^ sw;
      bf16x8 a[4], b[4];
      rd4(A, wr, col0, lr, a);
      rd4(B, wc, col0, lr, b);
      mfma16(a, b, (f32x4(*)[4])acc);
      rd4(A, wr, col1, lr, a);
      rd4(B, wc, col1, lr, b);
      WAITLGKM0();
      BAR(); SCHED0();
      if (t + 2 < nt) {
        const int k2 = kbase + (t + 2) * 64;
        stage_glds(Sb, NSUP, ti * 128, k2, clds + cb);
        if (!diag) stage_glds(Sb, NSUP, tj * 128, k2, clds + cb + 8192);
      }
      mfma16(a, b, (f32x4(*)[4])acc);
    }

    const float scale = 1.0f / (25599.0f + 1e-8f);
    const int rbase = ti * 128 + wr + (l >> 4) * 4;
    const int cbase = tj * 128 + wc + (l & 15);
#pragma unroll
    for (int i = 0; i < 4; ++i)
#pragma unroll
      for (int j = 0; j < 4; ++j)
#pragma unroll
        for (int r = 0; r < 4; ++r)
          atomicAdd(&cov[(size_t)(rbase + i * 16 + r) * CCH + cbase + j * 16],
                    acc[i][j][r] * scale);
  } else {
    // ---- qnorm job: 4 rows per block ----
    const int row = (bx - NCOVB) * 4 + (threadIdx.x >> 6);
    const int l = threadIdx.x & 63;
    const float4* src = (const float4*)(q + (size_t)row * DSP);
    float4 v[4];
    float ss = 0.f;
#pragma unroll
    for (int i = 0; i < 4; ++i) {
      v[i] = src[l + 64 * i];
      ss += v[i].x * v[i].x + v[i].y * v[i].y + v[i].z * v[i].z + v[i].w * v[i].w;
    }
#pragma unroll
    for (int off = 32; off > 0; off >>= 1) ss += __shfl_xor(ss, off);
    const float f = 1.0f / (sqrtf(ss) + 1e-8f);
    if (l == 0) qfac[row] = f;
#pragma unroll
    for (int i = 0; i < 4; ++i) {
      ushort4 o;
      o.x = f2bf(v[i].x * f); o.y = f2bf(v[i].y * f);
      o.z = f2bf(v[i].z * f); o.w = f2bf(v[i].w * f);
      *(ushort4*)(Qb + (size_t)row * DSP + (size_t)(l + 64 * i) * 4) = o;
    }
  }
}

// ---------------- gram256: per-query Gram x cov Frobenius, K-split x2 ----------------
// 1280 blocks = 8 xcd * 8 n * 10 pairs * 2 k-halves = exactly 5 rounds at
// 1 block/CU; same-n blocks share an XCD L2.
// Diag pairs: cov tile quadrant (1,0) is unwritten; by symmetry weight quadrant
// (0,1) x2, skip (1,0) (wave-uniform).
__global__ __launch_bounds__(512, 2) void gram256_kernel(
    const unsigned short* __restrict__ Qb, const float* __restrict__ cov,
    float* __restrict__ out) {
  __shared__ unsigned short lds[65536];   // 128 KB
  const int wg = blockIdx.x;
  const int xcd = wg & 7, slot = wg >> 3;        // slot 0..159
  const int n = xcd * 8 + slot / 20;
  const int sub = slot % 20;
  const int kh = sub & 1;
  int ti, tj; decode_pair4(sub >> 1, ti, tj);
  const bool diag = (ti == tj);
  const int tid = threadIdx.x, l = tid & 63, wid = tid >> 6;
  const int wm = wid >> 2, wn = wid & 3;
  const int lr = l & 15, kg = (l >> 4) * 8;
  const int sw = (lr & 7) << 3;
  const unsigned short* Qn = Qb + (size_t)n * CCH * DSP;

  f32x4 acc[8][4];
#pragma unroll
  for (int i = 0; i < 8; ++i)
#pragma unroll
    for (int j = 0; j < 4; ++j) acc[i][j] = 0.f;

  loop256<8>(Qn, DSP, ti * 256, tj * 256, kh * 512, diag, lds,
             wm, wn, lr, kg, sw, acc);

  float wgt;
  if (!diag) wgt = 2.0f;
  else if (wm == 0 && (wn >> 1) == 1) wgt = 2.0f;   // upper-right quadrant
  else if (wm == 1 && (wn >> 1) == 0) wgt = 0.0f;   // lower-left: cov unwritten
  else wgt = 1.0f;

  float s = 0.f;
  if (wgt != 0.0f) {
    const int rbase = ti * 256 + wm * 128 + (l >> 4) * 4;
    const int cbase = tj * 256 + wn * 64 + (l & 15);
#pragma unroll
    for (int i = 0; i < 8; ++i)
#pragma unroll
      for (int j = 0; j < 4; ++j)
#pragma unroll
        for (int r = 0; r < 4; ++r)
          s += acc[i][j][r] * cov[(size_t)(rbase + i * 16 + r) * CCH + cbase + j * 16];
  }
  s *= wgt * (1.0f / 1024.0f);
#pragma unroll
  for (int off = 32; off > 0; off >>= 1) s += __shfl_xor(s, off);
  if (l == 0) atomicAdd(&out[n], s);
}

// ---------------- f32 reg-staged fallback path (thin ws) — 128-tile scheme ----------------
__device__ inline void mfma16s(const bf16x8 a[4], const bf16x8 b[4], f32x4 acc[4][4]) {
#pragma unroll
  for (int i = 0; i < 4; ++i)
#pragma unroll
    for (int j = 0; j < 4; ++j)
      acc[i][j] = __builtin_amdgcn_mfma_f32_16x16x32_bf16(a[i], b[j], acc[i][j], 0, 0, 0);
}

__device__ inline void stage_sup_f32(const float* __restrict__ sup,
                                     const float* __restrict__ mean,
                                     int row0, int k0, unsigned short* lds) {
  const int tid = threadIdx.x;
#pragma unroll
  for (int it = 0; it < 4; ++it) {
    const int ci = it * 256 + tid;
    const int r = ci >> 3, kc = (ci & 7) << 3;
    const int c = row0 + r;
    const int k = k0 + kc;
    const int b = k >> 10, sp = k & 1023;
    const float4* gp = (const float4*)(sup + ((size_t)b * CCH + c) * DSP + sp);
    const float4 v0 = gp[0], v1 = gp[1];
    const float m = mean[c];
    union { unsigned short h[8]; int4 q; } pk;
    pk.h[0] = f2bf(v0.x - m); pk.h[1] = f2bf(v0.y - m);
    pk.h[2] = f2bf(v0.z - m); pk.h[3] = f2bf(v0.w - m);
    pk.h[4] = f2bf(v1.x - m); pk.h[5] = f2bf(v1.y - m);
    pk.h[6] = f2bf(v1.z - m); pk.h[7] = f2bf(v1.w - m);
    *(int4*)(lds + (size_t)(r * 8 + ((ci & 7) ^ (r & 7))) * 8) = pk.q;
  }
}
__device__ inline void stage_q_f32(const float* __restrict__ qn,
                                   const float* __restrict__ qfacn,
                                   int row0, int k0, unsigned short* lds) {
  const int tid = threadIdx.x;
#pragma unroll
  for (int it = 0; it < 4; ++it) {
    const int ci = it * 256 + tid;
    const int r = ci >> 3, kc = (ci & 7) << 3;
    const int c = row0 + r;
    const float4* gp = (const float4*)(qn + (size_t)c * DSP + k0 + kc);
    const float4 v0 = gp[0], v1 = gp[1];
    const float f = qfacn[c];
    union { unsigned short h[8]; int4 q; } pk;
    pk.h[0] = f2bf(v0.x * f); pk.h[1] = f2bf(v0.y * f);
    pk.h[2] = f2bf(v0.z * f); pk.h[3] = f2bf(v0.w * f);
    pk.h[4] = f2bf(v1.x * f); pk.h[5] = f2bf(v1.y * f);
    pk.h[6] = f2bf(v1.z * f); pk.h[7] = f2bf(v1.w * f);
    *(int4*)(lds + (size_t)(r * 8 + ((ci & 7) ^ (r & 7))) * 8) = pk.q;
  }
}
__device__ inline void compute_step(const unsigned short* lA, const unsigned short* lB,
                                    int wr, int wc, int lr, int kg, f32x4 acc[4][4]) {
  const int sc = (lr & 7) << 3;
#pragma unroll
  for (int kk = 0; kk < 64; kk += 32) {
    const int col = (kk + kg) ^ sc;
    bf16x8 a[4], b[4];
    rd4(lA, wr, col, lr, a);
    rd4(lB, wc, col, lr, b);
    mfma16s(a, b, acc);
  }
}

__global__ __launch_bounds__(256) void cov_kernel_f32(
    const float* __restrict__ sup, const float* __restrict__ mean,
    float* __restrict__ cov) {
  __shared__ unsigned short clds[32768];
  const int wg = blockIdx.x;
  const int ks = wg & 7;
  int ti, tj; decode_tile8(wg >> 3, ti, tj);
  const bool diag = (ti == tj);
  const int tid = threadIdx.x, l = tid & 63, w = tid >> 6;
  const int wr = (w >> 1) * 64, wc = (w & 1) * 64, lr = l & 15, kg = (l >> 4) * 8;
  f32x4 acc[4][4];
#pragma unroll
  for (int i = 0; i < 4; ++i)
#pragma unroll
    for (int j = 0; j < 4; ++j) acc[i][j] = 0.f;

  const int kbase = ks * (NSUP / 8);
  stage_sup_f32(sup, mean, ti * 128, kbase, clds);
  if (!diag) stage_sup_f32(sup, mean, tj * 128, kbase, clds + 8192);
  __syncthreads();
  for (int kt = 0; kt < 50; ++kt) {
    const int cb = (kt & 1) * 16384;
    const int nb = cb ^ 16384;
    if (kt + 1 < 50) {
      const int k1 = kbase + (kt + 1) * 64;
      stage_sup_f32(sup, mean, ti * 128, k1, clds + nb);
      if (!diag) stage_sup_f32(sup, mean, tj * 128, k1, clds + nb + 8192);
    }
    compute_step(clds + cb, diag ? clds + cb : clds + cb + 8192, wr, wc, lr, kg, acc);
    __syncthreads();
  }
  const float scale = 1.0f / (25599.0f + 1e-8f);
  const int rbase = ti * 128 + wr + (l >> 4) * 4;
  const int cbase = tj * 128 + wc + (l & 15);
#pragma unroll
  for (int i = 0; i < 4; ++i)
#pragma unroll
    for (int j = 0; j < 4; ++j)
#pragma unroll
      for (int r = 0; r < 4; ++r)
        atomicAdd(&cov[(size_t)(rbase + i * 16 + r) * CCH + cbase + j * 16],
                  acc[i][j][r] * scale);
}

__global__ __launch_bounds__(256) void gram_kernel_f32(
    const float* __restrict__ q, const float* __restrict__ qfac,
    const float* __restrict__ cov, float* __restrict__ out) {
  __shared__ unsigned short lA[2][128 * 64];
  __shared__ unsigned short lB[2][128 * 64];
  const int wg = blockIdx.x;
  const int xcd = wg & 7, slot = wg >> 3;
  const int n = xcd * 8 + slot / 36;
  int ti, tj; decode_tile8(slot % 36, ti, tj);
  const bool diag = (ti == tj);
  const int tid = threadIdx.x, l = tid & 63, w = tid >> 6;
  const int wr = (w >> 1) * 64, wc = (w & 1) * 64, lr = l & 15, kg = (l >> 4) * 8;
  f32x4 acc[4][4];
#pragma unroll
  for (int i = 0; i < 4; ++i)
#pragma unroll
    for (int j = 0; j < 4; ++j) acc[i][j] = 0.f;

  const float* qn = q + (size_t)n * CCH * DSP;
  const float* qfacn = qfac + (size_t)n * CCH;

  stage_q_f32(qn, qfacn, ti * 128, 0, lA[0]);
  if (!diag) stage_q_f32(qn, qfacn, tj * 128, 0, lB[0]);
  __syncthreads();
  int cur = 0;
  for (int kt = 0; kt < 16; ++kt) {
    if (kt + 1 < 16) {
      const int k1 = (kt + 1) * 64;
      stage_q_f32(qn, qfacn, ti * 128, k1, lA[cur ^ 1]);
      if (!diag) stage_q_f32(qn, qfacn, tj * 128, k1, lB[cur ^ 1]);
    }
    compute_step(lA[cur], diag ? lA[cur] : lB[cur], wr, wc, lr, kg, acc);
    __syncthreads();
    cur ^= 1;
  }

  float s = 0.f;
  const int rbase = ti * 128 + wr + (l >> 4) * 4;
  const int cbase = tj * 128 + wc + (l & 15);
#pragma unroll
  for (int i = 0; i < 4; ++i)
#pragma unroll
    for (int j = 0; j < 4; ++j)
#pragma unroll
      for (int r = 0; r < 4; ++r)
        s += acc[i][j][r] * cov[(size_t)(rbase + i * 16 + r) * CCH + cbase + j * 16];
  if (!diag) s *= 2.0f;
  s *= (1.0f / 1024.0f);
#pragma unroll
  for (int off = 32; off > 0; off >>= 1) s += __shfl_xor(s, off);
  if (l == 0) atomicAdd(&out[n], s);
}

// ---------------- launch ----------------
extern "C" void kernel_launch(void* const* d_in, const int* in_sizes, int n_in,
                              void* d_out, int out_size, void* d_ws, size_t ws_size,
                              hipStream_t stream) {
  const float* q = (const float*)d_in[0];
  const float* sup = (const float*)d_in[1];
  float* out = (float*)d_out;

  char* ws = (char*)d_ws;
  float* mean = (float*)ws;                                  // 4 KB
  float* qfac = (float*)(ws + (4 << 10));                    // 256 KB
  float* cov  = (float*)(ws + (4 << 10) + (256 << 10));      // 4 MB
  unsigned short* Sb = (unsigned short*)(ws + (4 << 10) + (256 << 10) + (4 << 20));
  unsigned short* Qb = Sb + (size_t)CCH * NSUP;
  const size_t need_fat = (size_t)(4 << 10) + (256 << 10) + (4 << 20) +
                          (size_t)CCH * NSUP * 2 + (size_t)NQ * CCH * DSP * 2;
  const bool fat = ws_size >= need_fat;

  mean_center_kernel<<<CCH, 640, 0, stream>>>(sup, mean, Sb, fat ? 1 : 0,
                                              (float4*)cov, (float4*)out);

  if (fat) {
    covq_kernel<<<dim3(NCOVB + NQ * CCH / 4), 256, 0, stream>>>(Sb, cov, q, qfac, Qb);
    gram256_kernel<<<dim3(1280), 512, 0, stream>>>(Qb, cov, out);
  } else {
    qnorm_kernel<<<NQ * CCH / 4, 256, 0, stream>>>(q, qfac, (unsigned short*)0, 0);
    cov_kernel_f32<<<dim3(288), 256, 0, stream>>>(sup, mean, cov);
    gram_kernel_f32<<<dim3(8 * 8 * 36), 256, 0, stream>>>(q, qfac, cov, out);
  }
}